// Round 4
// baseline (675.799 us; speedup 1.0000x reference)
//
#include <hip/hip_runtime.h>
#include <hip/hip_bf16.h>

#define B_ 128
#define L_ 1024
#define T_ 512   // L/2 tokens per parity
#define D_ 768
#define CH_ 96   // D/8 chunks of 8 elems
#define DT_ 513  // output tokens per batch
#define TAU 5e-5f

typedef __attribute__((ext_vector_type(8))) short bf16x8;
typedef __attribute__((ext_vector_type(4))) float f32x4;

__device__ __forceinline__ unsigned short f2bf_rne(float x){
    unsigned u = __float_as_uint(x);
    unsigned r = (u + 0x7FFFu + ((u >> 16) & 1u)) >> 16;
    return (unsigned short)r;
}
__device__ __forceinline__ float bf2f(unsigned short h){
    return __uint_as_float(((unsigned)h) << 16);
}

// ---------------- pack2: ALL tokens -> fp64 norm + hi/lo bf16 split, chunk-major per parity ----------------
// packed layout: P[((b*96 + c)*512 + tok)*8 + e], tok = seq>>1, array chosen by seq&1.
__global__ __launch_bounds__(256) void pack2_k(const float* __restrict__ hs,
                                               unsigned short* __restrict__ Ahg,
                                               unsigned short* __restrict__ Alg,
                                               unsigned short* __restrict__ Bhg,
                                               unsigned short* __restrict__ Blg,
                                               double* __restrict__ nsq,
                                               int* __restrict__ flagcnt){
    __shared__ __align__(16) unsigned short LhS[CH_ * 16 * 8];  // 24.6 KB
    __shared__ __align__(16) unsigned short LlS[CH_ * 16 * 8];
    if (blockIdx.x == 0 && threadIdx.x == 0) *flagcnt = 0;
    int b = blockIdx.x >> 6, g = blockIdx.x & 63;   // 16 seq tokens per block
    int wv = threadIdx.x >> 6, lane = threadIdx.x & 63;

    #pragma unroll
    for (int rr = 0; rr < 4; ++rr){
        int jj = wv * 4 + rr;                       // 0..15 within block
        long seq = (long)b * L_ + g * 16 + jj;
        const float4* src = (const float4*)(hs + seq * D_);
        float4 f0 = src[lane], f1 = src[lane + 64], f2 = src[lane + 128];
        double s = 0.0;
        s += (double)f0.x*f0.x + (double)f0.y*f0.y + (double)f0.z*f0.z + (double)f0.w*f0.w;
        s += (double)f1.x*f1.x + (double)f1.y*f1.y + (double)f1.z*f1.z + (double)f1.w*f1.w;
        s += (double)f2.x*f2.x + (double)f2.y*f2.y + (double)f2.z*f2.z + (double)f2.w*f2.w;
        #pragma unroll
        for (int off = 32; off; off >>= 1) s += __shfl_xor(s, off);
        if (lane == 0 && (jj & 1)) nsq[seq] = s;    // odd-token norms for exact_k
        float rn = (float)(1.0 / sqrt(s));
        float4 fv[3] = {f0, f1, f2};
        #pragma unroll
        for (int t = 0; t < 3; ++t){
            int e0 = t * 256 + lane * 4;
            int c = e0 >> 3, ei = e0 & 7;           // ei = 0 or 4
            float vv[4] = {fv[t].x, fv[t].y, fv[t].z, fv[t].w};
            short4 hv, lv;
            #pragma unroll
            for (int e = 0; e < 4; ++e){
                float a = vv[e] * rn;
                unsigned short h = f2bf_rne(a);
                unsigned short l = f2bf_rne(a - bf2f(h));
                ((short*)&hv)[e] = (short)h; ((short*)&lv)[e] = (short)l;
            }
            int o = c * 128 + ((jj ^ (c & 7)) << 3) + ei;   // XOR-swizzled (shorts)
            *(short4*)(LhS + o) = hv;
            *(short4*)(LlS + o) = lv;
        }
    }
    __syncthreads();
    // write out: per (c,jj) one bf16x8; jj parity selects target array
    #pragma unroll
    for (int it = 0; it < 6; ++it){
        int linear = it * 256 + threadIdx.x;
        int c = linear >> 4, jj = linear & 15;
        int o = c * 128 + ((jj ^ (c & 7)) << 3);
        int tok = g * 8 + (jj >> 1);
        long go = ((long)(b * CH_ + c) * T_ + tok) * 8;
        if (jj & 1){
            *(bf16x8*)(Bhg + go) = *(const bf16x8*)(LhS + o);
            *(bf16x8*)(Blg + go) = *(const bf16x8*)(LlS + o);
        } else {
            *(bf16x8*)(Ahg + go) = *(const bf16x8*)(LhS + o);
            *(bf16x8*)(Alg + go) = *(const bf16x8*)(LlS + o);
        }
    }
}

// ---------------- scores: barrier-free, all-packed-operand MFMA, fused argmax+flag ----------------
// block tile: 64 A-rows (it) x ALL 512 B-cols; wave wv owns cols wv*128..+127.
// bid mapping: same-b blocks are bid-adjacent (stride 8) on one XCD for B L2 reuse.
__global__ __launch_bounds__(256, 2) void scores_k(const unsigned short* __restrict__ Ahg,
                                                   const unsigned short* __restrict__ Alg,
                                                   const unsigned short* __restrict__ Bhg,
                                                   const unsigned short* __restrict__ Blg,
                                                   int* __restrict__ node_idx,
                                                   int* __restrict__ flagcnt,
                                                   int* __restrict__ flaglist){
    __shared__ float pm1s[64][4];
    __shared__ float pm2s[64][4];
    __shared__ int   pjs[64][4];

    int bid = blockIdx.x;                 // 1024 blocks
    int xcd = bid & 7, it = (bid >> 3) & 7, bslot = bid >> 6;
    int b = xcd * 16 + bslot;

    int tid = threadIdx.x;
    int wv = tid >> 6, lane = tid & 63, l15 = lane & 15, l4 = lane >> 4;

    const unsigned short* pAh = Ahg + ((long)(b * CH_ + l4) * T_ + it * 64 + l15) * 8;
    const unsigned short* pAl = Alg + ((long)(b * CH_ + l4) * T_ + it * 64 + l15) * 8;
    const unsigned short* pBh = Bhg + ((long)(b * CH_ + l4) * T_ + wv * 128 + l15) * 8;
    const unsigned short* pBl = Blg + ((long)(b * CH_ + l4) * T_ + wv * 128 + l15) * 8;

    f32x4 acc[4][8];
    #pragma unroll
    for (int i = 0; i < 4; ++i)
        #pragma unroll
        for (int j = 0; j < 8; ++j) acc[i][j] = (f32x4){0.f, 0.f, 0.f, 0.f};

    for (int s = 0; s < 24; ++s){
        long ko = (long)s * (4 * T_ * 8);          // advance 4 k-chunks per step
        bf16x8 ah[4], al[4];
        #pragma unroll
        for (int ib = 0; ib < 4; ++ib){
            ah[ib] = *(const bf16x8*)(pAh + ko + ib * 128);
            al[ib] = *(const bf16x8*)(pAl + ko + ib * 128);
        }
        #pragma unroll
        for (int half = 0; half < 2; ++half){
            bf16x8 bh[4], bl[4];
            #pragma unroll
            for (int j4 = 0; j4 < 4; ++j4){
                bh[j4] = *(const bf16x8*)(pBh + ko + (half * 4 + j4) * 128);
                bl[j4] = *(const bf16x8*)(pBl + ko + (half * 4 + j4) * 128);
            }
            // per-acc k-order: hh, hl, lh  (bit-identical to prior rounds)
            #pragma unroll
            for (int j4 = 0; j4 < 4; ++j4)
                #pragma unroll
                for (int ib = 0; ib < 4; ++ib)
                    acc[ib][half*4+j4] = __builtin_amdgcn_mfma_f32_16x16x32_bf16(ah[ib], bh[j4], acc[ib][half*4+j4], 0, 0, 0);
            #pragma unroll
            for (int j4 = 0; j4 < 4; ++j4)
                #pragma unroll
                for (int ib = 0; ib < 4; ++ib)
                    acc[ib][half*4+j4] = __builtin_amdgcn_mfma_f32_16x16x32_bf16(ah[ib], bl[j4], acc[ib][half*4+j4], 0, 0, 0);
            #pragma unroll
            for (int j4 = 0; j4 < 4; ++j4)
                #pragma unroll
                for (int ib = 0; ib < 4; ++ib)
                    acc[ib][half*4+j4] = __builtin_amdgcn_mfma_f32_16x16x32_bf16(al[ib], bh[j4], acc[ib][half*4+j4], 0, 0, 0);
        }
    }

    // epilogue: per-row max1/argmax/max2; C layout: row = ib*16 + l4*4 + rr, col = wv*128 + jb*16 + l15
    #pragma unroll
    for (int ib = 0; ib < 4; ++ib)
        #pragma unroll
        for (int rr = 0; rr < 4; ++rr){
            float m1 = -1e30f, m2 = -1e30f; int j1 = 0;
            #pragma unroll
            for (int jb = 0; jb < 8; ++jb){          // ascending cols: strict > keeps lowest j
                float v2 = acc[ib][jb][rr];
                int col = wv * 128 + jb * 16 + l15;
                if (v2 > m1){ m2 = m1; m1 = v2; j1 = col; }
                else m2 = fmaxf(m2, v2);
            }
            #pragma unroll
            for (int m = 1; m < 16; m <<= 1){
                float o1 = __shfl_xor(m1, m);
                float o2 = __shfl_xor(m2, m);
                int   oj = __shfl_xor(j1, m);
                if (o1 > m1){ m2 = fmaxf(m1, o2); m1 = o1; j1 = oj; }
                else if (o1 < m1){ m2 = fmaxf(m2, o1); }
                else { m2 = m1; j1 = min(j1, oj); }  // exact tie -> margin 0 -> rescued
            }
            if (l15 == 0){
                int row = ib * 16 + l4 * 4 + rr;
                pm1s[row][wv] = m1; pm2s[row][wv] = m2; pjs[row][wv] = j1;
            }
        }
    __syncthreads();
    if (tid < 64){
        float M1 = -1e30f, M2 = -1e30f; int J1 = 0;
        #pragma unroll
        for (int w2 = 0; w2 < 4; ++w2){              // ascending col blocks
            float a1 = pm1s[tid][w2], a2 = pm2s[tid][w2]; int aj = pjs[tid][w2];
            if (a1 > M1){ M2 = fmaxf(M1, a2); M1 = a1; J1 = aj; }
            else M2 = fmaxf(M2, a1);
        }
        int i = it * 64 + tid;
        int t = b * T_ + i;
        node_idx[t] = J1;
        if (i != 0 && (M1 - M2) < TAU){
            int p = atomicAdd(flagcnt, 1);
            flaglist[p] = t;
        }
    }
}

// ---------------- fp64 exact rescore of flagged rows ----------------
__global__ __launch_bounds__(256) void exact_k(const float* __restrict__ hs,
                                               const double* __restrict__ nsq,
                                               const int* __restrict__ flagcnt,
                                               const int* __restrict__ flaglist,
                                               int* __restrict__ node_idx){
    __shared__ float arow[D_];
    __shared__ double wbv[4];
    __shared__ int wbj[4];
    int nf = *flagcnt;
    for (int f = blockIdx.x; f < nf; f += gridDim.x){
        __syncthreads();
        int t = flaglist[f];
        int b = t >> 9, i = t & 511;
        for (int d = threadIdx.x; d < D_; d += 256)
            arow[d] = hs[((long)b * L_ + 2 * i) * D_ + d];
        __syncthreads();
        int wv = threadIdx.x >> 6, lane = threadIdx.x & 63;
        double bv = -1e300; int bj = -1;
        for (int j = wv; j < T_; j += 4){
            const float* brow = hs + ((long)b * L_ + 2 * j + 1) * D_;
            double s = 0.0;
            #pragma unroll
            for (int dd = 0; dd < 12; ++dd){
                int d = dd * 64 + lane;
                s += (double)arow[d] * (double)brow[d];
            }
            #pragma unroll
            for (int off = 32; off; off >>= 1) s += __shfl_xor(s, off);
            double sc = s / sqrt(nsq[(long)b * L_ + 2 * j + 1]); // row-uniform 1/|a_i| dropped
            if (sc > bv){ bv = sc; bj = j; }
        }
        if (lane == 0){ wbv[wv] = bv; wbj[wv] = bj; }
        __syncthreads();
        if (threadIdx.x == 0){
            double BV = -1e300; int BJ = 1 << 30;
            #pragma unroll
            for (int w2 = 0; w2 < 4; ++w2)
                if (wbv[w2] > BV || (wbv[w2] == BV && wbj[w2] < BJ)){ BV = wbv[w2]; BJ = wbj[w2]; }
            node_idx[t] = BJ;
        }
        __syncthreads();
    }
}

// ---------------- deterministic CSR (stable by source index) ----------------
__global__ __launch_bounds__(512) void csr_k(const int* __restrict__ node_idx,
                                             int* __restrict__ goff,
                                             int* __restrict__ glist){
    __shared__ int sidx[512];
    __shared__ int off[513];
    __shared__ int tmp[512];
    int b = blockIdx.x, t = threadIdx.x;
    sidx[t] = node_idx[b * T_ + t];
    __shared__ int cnt[512];
    cnt[t] = 0;
    __syncthreads();
    if (t >= 1) atomicAdd(&cnt[sidx[t]], 1);   // i=0 excluded (always unmerged)
    __syncthreads();
    tmp[t] = cnt[t];
    __syncthreads();
    for (int s = 1; s < 512; s <<= 1){
        int v = (t >= s) ? tmp[t - s] : 0;
        __syncthreads();
        tmp[t] += v;
        __syncthreads();
    }
    if (t == 0) off[0] = 0;
    off[t + 1] = tmp[t];
    __syncthreads();
    if (t >= 1){
        int j = sidx[t], r = 0;
        for (int i2 = 1; i2 < t; ++i2) r += (sidx[i2] == j);  // stable rank
        glist[b * T_ + off[j] + r] = t;
    }
    goff[b * 513 + t] = off[t];
    if (t == 0) goff[b * 513 + 512] = off[512];
}

// ---------------- merge: gather sources per dst, mean, write (+mask) ----------------
__global__ __launch_bounds__(256) void merge_k(const float* __restrict__ hs,
                                               const int* __restrict__ goff,
                                               const int* __restrict__ glist,
                                               float* __restrict__ out){
    int bid = blockIdx.x;
    int b = bid / DT_, jj = bid - b * DT_;
    long obase = ((long)b * DT_ + jj) * D_;
    if (threadIdx.x == 0) out[(long)B_ * DT_ * D_ + b * DT_ + jj] = 0.0f;  // mask
    int d0 = threadIdx.x, d1 = d0 + 256, d2 = d0 + 512;
    if (jj == 0){  // unmerged token = src[0] = seq 0
        const float* src = hs + (long)b * L_ * D_;
        out[obase + d0] = src[d0]; out[obase + d1] = src[d1]; out[obase + d2] = src[d2];
        return;
    }
    int j = jj - 1;
    int o0 = goff[b * 513 + j], o1 = goff[b * 513 + j + 1];
    const float* dst = hs + ((long)b * L_ + 2 * j + 1) * D_;
    float a0 = dst[d0], a1 = dst[d1], a2 = dst[d2];
    for (int s = o0; s < o1; ++s){   // ascending source index: deterministic
        int i = glist[b * T_ + s];
        const float* srow = hs + ((long)b * L_ + 2 * i) * D_;
        a0 += srow[d0]; a1 += srow[d1]; a2 += srow[d2];
    }
    float cnt = (float)(o1 - o0 + 1);
    out[obase + d0] = a0 / cnt;
    out[obase + d1] = a1 / cnt;
    out[obase + d2] = a2 / cnt;
}

extern "C" void kernel_launch(void* const* d_in, const int* in_sizes, int n_in,
                              void* d_out, int out_size, void* d_ws, size_t ws_size,
                              hipStream_t stream){
    const float* hs = (const float*)d_in[0];  // (128,1024,768) f32
    float* out = (float*)d_out;
    char* ws = (char*)d_ws;

    const long PSZ = (long)B_ * CH_ * T_ * 8;          // 50,331,648 shorts = 100.66 MB
    unsigned short* Ahg = (unsigned short*)(ws);
    unsigned short* Alg = Ahg + PSZ;
    unsigned short* Bhg = Alg + PSZ;
    unsigned short* Blg = Bhg + PSZ;                   // packed total 402.7 MB (ws ~1.5 GiB)
    char* ws2 = (char*)(Blg + PSZ);

    double* nsq      = (double*)(ws2 + 0);        // 1048576 B (odd entries valid)
    int*    node_idx = (int*)   (ws2 + 1048576);  // 262144 B
    int*    flagcnt  = (int*)   (ws2 + 1310720);  // 256 B
    int*    flaglist = (int*)   (ws2 + 1310976);  // 262144 B
    int*    goff     = (int*)   (ws2 + 1573120);  // 263168 B
    int*    glist    = (int*)   (ws2 + 1836288);  // 262144 B

    pack2_k <<<B_ * 64, 256, 0, stream>>>(hs, Ahg, Alg, Bhg, Blg, nsq, flagcnt);
    scores_k<<<B_ * 8, 256, 0, stream>>>(Ahg, Alg, Bhg, Blg, node_idx, flagcnt, flaglist);
    exact_k <<<256, 256, 0, stream>>>(hs, nsq, flagcnt, flaglist, node_idx);
    csr_k   <<<B_, 512, 0, stream>>>(node_idx, goff, glist);
    merge_k <<<B_ * DT_, 256, 0, stream>>>(hs, goff, glist, out);
}

// Round 5
// 457.531 us; speedup vs baseline: 1.4771x; 1.4771x over previous
//
#include <hip/hip_runtime.h>
#include <hip/hip_bf16.h>

#define B_ 128
#define L_ 1024
#define T_ 512   // L/2 tokens per parity
#define D_ 768
#define CH_ 96   // D/8 chunks of 8 elems
#define DT_ 513  // output tokens per batch
#define TAU_C 1e-3f   // coarse candidate window (~12 sigma of bf16 coarse error)

typedef __attribute__((ext_vector_type(8))) short bf16x8;
typedef __attribute__((ext_vector_type(4))) float f32x4;

typedef const __attribute__((address_space(1))) unsigned int* gas1_t;
typedef __attribute__((address_space(3))) unsigned int* gas3_t;

__device__ __forceinline__ unsigned short f2bf_rne(float x){
    unsigned u = __float_as_uint(x);
    unsigned r = (u + 0x7FFFu + ((u >> 16) & 1u)) >> 16;
    return (unsigned short)r;
}

// ---------------- pack: ALL tokens -> fp64 norm + single bf16, chunk-major per parity ----------------
// packed layout: P[((b*96 + c)*512 + tok)*8 + e], tok = seq>>1, array by seq&1.
__global__ __launch_bounds__(256) void pack_k(const float* __restrict__ hs,
                                              unsigned short* __restrict__ Apk,
                                              unsigned short* __restrict__ Bpk,
                                              double* __restrict__ nsq,
                                              int* __restrict__ paircnt){
    __shared__ __align__(16) unsigned short LhS[CH_ * 16 * 8];  // 24.6 KB
    if (blockIdx.x == 0 && threadIdx.x == 0) *paircnt = 0;
    int b = blockIdx.x >> 6, g = blockIdx.x & 63;   // 16 seq tokens per block
    int wv = threadIdx.x >> 6, lane = threadIdx.x & 63;

    #pragma unroll
    for (int rr = 0; rr < 4; ++rr){
        int jj = wv * 4 + rr;                       // 0..15 within block
        long seq = (long)b * L_ + g * 16 + jj;
        const float4* src = (const float4*)(hs + seq * D_);
        float4 f0 = src[lane], f1 = src[lane + 64], f2 = src[lane + 128];
        double s = 0.0;
        s += (double)f0.x*f0.x + (double)f0.y*f0.y + (double)f0.z*f0.z + (double)f0.w*f0.w;
        s += (double)f1.x*f1.x + (double)f1.y*f1.y + (double)f1.z*f1.z + (double)f1.w*f1.w;
        s += (double)f2.x*f2.x + (double)f2.y*f2.y + (double)f2.z*f2.z + (double)f2.w*f2.w;
        #pragma unroll
        for (int off = 32; off; off >>= 1) s += __shfl_xor(s, off);
        if (lane == 0 && (jj & 1)) nsq[seq] = s;    // odd-token norms for refine
        float rn = (float)(1.0 / sqrt(s));
        float4 fv[3] = {f0, f1, f2};
        #pragma unroll
        for (int t = 0; t < 3; ++t){
            int e0 = t * 256 + lane * 4;
            int c = e0 >> 3, ei = e0 & 7;           // ei = 0 or 4
            float vv[4] = {fv[t].x, fv[t].y, fv[t].z, fv[t].w};
            short4 hv;
            #pragma unroll
            for (int e = 0; e < 4; ++e)
                ((short*)&hv)[e] = (short)f2bf_rne(vv[e] * rn);
            int o = c * 128 + ((jj ^ (c & 7)) << 3) + ei;   // XOR-swizzled (shorts)
            *(short4*)(LhS + o) = hv;
        }
    }
    __syncthreads();
    #pragma unroll
    for (int it = 0; it < 6; ++it){
        int linear = it * 256 + threadIdx.x;
        int c = linear >> 4, jj = linear & 15;
        int o = c * 128 + ((jj ^ (c & 7)) << 3);
        int tok = g * 8 + (jj >> 1);
        long go = ((long)(b * CH_ + c) * T_ + tok) * 8;
        if (jj & 1) *(bf16x8*)(Bpk + go) = *(const bf16x8*)(LhS + o);
        else        *(bf16x8*)(Apk + go) = *(const bf16x8*)(LhS + o);
    }
}

// ---------------- coarse: single-pass bf16 MFMA, B via global_load_lds dbuf, fused candidates ----------------
// block: M=128 A-rows (it) x N=512 (all B cols); 8 waves (wr=w>>2, wc=w&3); wave tile 64x128.
__global__ __launch_bounds__(512, 2) void coarse_k(const unsigned short* __restrict__ Apk,
                                                   const unsigned short* __restrict__ Bpk,
                                                   int* __restrict__ node_idx,
                                                   unsigned long long* __restrict__ rowkey,
                                                   int* __restrict__ paircnt,
                                                   int2* __restrict__ pairs){
    // B staged tok-major: LDS[tok][c'][8 bf16] -> fragment reads are 1KB-contiguous (conflict-free)
    __shared__ __align__(16) unsigned short Bb[2][16384];   // 2 x 32 KB

    int bid = blockIdx.x;                 // 512 blocks
    int xcd = bid & 7, q = bid >> 3, it = q & 3, bhi = q >> 2;
    int b = xcd + 8 * bhi;                // same-b blocks adjacent on one XCD (B L2 reuse)

    int tid = threadIdx.x, w = tid >> 6, lane = tid & 63;
    int wr = w >> 2, wc = w & 3, l15 = lane & 15, l4 = lane >> 4;

    int lc = lane & 3, lt = lane >> 2;    // staging: chunk-of-4, token-of-16
    long pkbase = (long)b * CH_ * T_;     // shorts/8

    f32x4 acc[4][8];
    #pragma unroll
    for (int i = 0; i < 4; ++i)
        #pragma unroll
        for (int j = 0; j < 8; ++j) acc[i][j] = (f32x4){0.f, 0.f, 0.f, 0.f};

    int arow = it * 128 + wr * 64 + l15;

    // prologue: stage B step0 -> buf0; load A frags step0
    #pragma unroll
    for (int n = 0; n < 4; ++n){
        int qq = w + 8 * n;
        const unsigned short* src = Bpk + (pkbase + (long)(0 + lc) * T_ + qq * 16 + lt) * 8;
        __builtin_amdgcn_global_load_lds((gas1_t)src, (gas3_t)&Bb[0][qq * 512], 16, 0, 0);
    }
    bf16x8 ah[4];
    #pragma unroll
    for (int ib = 0; ib < 4; ++ib)
        ah[ib] = *(const bf16x8*)(Apk + (pkbase + (long)l4 * T_ + arow + ib * 16) * 8);
    __syncthreads();

    for (int s = 0; s < 24; ++s){
        int buf = s & 1;
        bf16x8 ahn[4];
        if (s < 23){
            int s4n = (s + 1) * 4;
            #pragma unroll
            for (int n = 0; n < 4; ++n){
                int qq = w + 8 * n;
                const unsigned short* src = Bpk + (pkbase + (long)(s4n + lc) * T_ + qq * 16 + lt) * 8;
                __builtin_amdgcn_global_load_lds((gas1_t)src, (gas3_t)&Bb[buf ^ 1][qq * 512], 16, 0, 0);
            }
            #pragma unroll
            for (int ib = 0; ib < 4; ++ib)
                ahn[ib] = *(const bf16x8*)(Apk + (pkbase + (long)(s4n + l4) * T_ + arow + ib * 16) * 8);
        }
        const char* Bcur = (const char*)&Bb[buf][0];
        #pragma unroll
        for (int jb = 0; jb < 8; ++jb){
            bf16x8 bh = *(const bf16x8*)(Bcur + (wc * 128 + jb * 16 + l15) * 64 + l4 * 16);
            #pragma unroll
            for (int ib = 0; ib < 4; ++ib)
                acc[ib][jb] = __builtin_amdgcn_mfma_f32_16x16x32_bf16(ah[ib], bh, acc[ib][jb], 0, 0, 0);
        }
        __syncthreads();
        if (s < 23){
            #pragma unroll
            for (int ib = 0; ib < 4; ++ib) ah[ib] = ahn[ib];
        }
    }

    // epilogue overlays in Bb
    char* ep = (char*)&Bb[0][0];
    float* pm1 = (float*)ep;             // [128][4]
    int*   pj  = (int*)(ep + 2048);      // [128][4]
    float* m1f = (float*)(ep + 4096);    // [128]
    int*   cnd = (int*)(ep + 4608);      // [128]

    // stage 1: per-row max/argmax within wave's 128 cols
    #pragma unroll
    for (int ib = 0; ib < 4; ++ib)
        #pragma unroll
        for (int rr = 0; rr < 4; ++rr){
            float m1 = -1e30f; int j1 = 0;
            #pragma unroll
            for (int jb = 0; jb < 8; ++jb){   // ascending cols: strict > keeps lowest j
                float v = acc[ib][jb][rr];
                int col = wc * 128 + jb * 16 + l15;
                if (v > m1){ m1 = v; j1 = col; }
            }
            #pragma unroll
            for (int m = 1; m < 16; m <<= 1){
                float o1 = __shfl_xor(m1, m);
                int   oj = __shfl_xor(j1, m);
                if (o1 > m1 || (o1 == m1 && oj < j1)){ m1 = o1; j1 = oj; }
            }
            if (l15 == 0){
                int row = wr * 64 + ib * 16 + l4 * 4 + rr;
                pm1[row * 4 + wc] = m1; pj[row * 4 + wc] = j1;
            }
        }
    __syncthreads();
    int grow0 = b * T_ + it * 128;
    if (tid < 128){
        float M1 = -1e30f; int J1 = 0;
        #pragma unroll
        for (int c2 = 0; c2 < 4; ++c2){   // ascending col blocks: ties keep lower j
            float a1 = pm1[tid * 4 + c2]; int aj = pj[tid * 4 + c2];
            if (a1 > M1){ M1 = a1; J1 = aj; }
        }
        node_idx[grow0 + tid] = J1;
        m1f[tid] = M1;
        cnd[tid] = 0;
        rowkey[grow0 + tid] = 0ULL;
    }
    __syncthreads();
    // candidate count
    #pragma unroll
    for (int ib = 0; ib < 4; ++ib)
        #pragma unroll
        for (int rr = 0; rr < 4; ++rr){
            int row = wr * 64 + ib * 16 + l4 * 4 + rr;
            float thr_ = m1f[row] - TAU_C;
            int hits = 0;
            #pragma unroll
            for (int jb = 0; jb < 8; ++jb) hits += (acc[ib][jb][rr] > thr_) ? 1 : 0;
            if (hits) atomicAdd(&cnd[row], hits);
        }
    __syncthreads();
    // emit refine pairs (includes the argmax itself) for rows with >=2 candidates
    #pragma unroll
    for (int ib = 0; ib < 4; ++ib)
        #pragma unroll
        for (int rr = 0; rr < 4; ++rr){
            int row = wr * 64 + ib * 16 + l4 * 4 + rr;
            if (cnd[row] < 2) continue;
            if (it == 0 && row == 0) continue;       // i=0 always unmerged
            float thr_ = m1f[row] - TAU_C;
            #pragma unroll
            for (int jb = 0; jb < 8; ++jb)
                if (acc[ib][jb][rr] > thr_){
                    int p = atomicAdd(paircnt, 1);
                    pairs[p] = make_int2(grow0 + row, wc * 128 + jb * 16 + l15);
                }
        }
}

// ---------------- refine: fp64 exact score for candidate pairs, atomicMax keyed winner ----------------
__global__ __launch_bounds__(256) void refine_k(const float* __restrict__ hs,
                                                const double* __restrict__ nsq,
                                                const int* __restrict__ paircnt,
                                                const int2* __restrict__ pairs,
                                                unsigned long long* __restrict__ rowkey){
    int n = *paircnt;
    int w = threadIdx.x >> 6, lane = threadIdx.x & 63;
    for (int p = blockIdx.x * 4 + w; p < n; p += gridDim.x * 4){
        int2 pr = pairs[p];
        int grow = pr.x, j = pr.y;
        int b = grow >> 9, i = grow & 511;
        const float* ar = hs + ((long)b * L_ + 2 * i) * D_;
        const float* br = hs + ((long)b * L_ + 2 * j + 1) * D_;
        double s = 0.0;
        #pragma unroll
        for (int dd = 0; dd < 12; ++dd){
            int d = dd * 64 + lane;
            s += (double)ar[d] * (double)br[d];
        }
        #pragma unroll
        for (int off = 32; off; off >>= 1) s += __shfl_xor(s, off);
        if (lane == 0){
            double sc = s / sqrt(nsq[(long)b * L_ + 2 * j + 1]);  // row-uniform 1/|a_i| dropped
            unsigned long long bits = (unsigned long long)__double_as_longlong(sc);
            unsigned long long key = (bits >> 63) ? ~bits : (bits | 0x8000000000000000ULL);
            key = (key & ~0xFFFFULL) | (unsigned long long)(511 - j);  // ties -> lowest j
            atomicMax(&rowkey[grow], key);
        }
    }
}

// ---------------- deterministic CSR (stable by source index), rowkey override ----------------
__global__ __launch_bounds__(512) void csr_k(const int* __restrict__ node_idx,
                                             const unsigned long long* __restrict__ rowkey,
                                             int* __restrict__ goff,
                                             int* __restrict__ glist){
    __shared__ int sidx[512];
    __shared__ int off[513];
    __shared__ int tmp[512];
    __shared__ int cnt[512];
    int b = blockIdx.x, t = threadIdx.x;
    unsigned long long rk = rowkey[b * T_ + t];
    sidx[t] = rk ? (511 - (int)(rk & 0xFFFFULL)) : node_idx[b * T_ + t];
    cnt[t] = 0;
    __syncthreads();
    if (t >= 1) atomicAdd(&cnt[sidx[t]], 1);   // i=0 excluded (always unmerged)
    __syncthreads();
    tmp[t] = cnt[t];
    __syncthreads();
    for (int s = 1; s < 512; s <<= 1){
        int v = (t >= s) ? tmp[t - s] : 0;
        __syncthreads();
        tmp[t] += v;
        __syncthreads();
    }
    if (t == 0) off[0] = 0;
    off[t + 1] = tmp[t];
    __syncthreads();
    if (t >= 1){
        int j = sidx[t], r = 0;
        for (int i2 = 1; i2 < t; ++i2) r += (sidx[i2] == j);  // stable rank
        glist[b * T_ + off[j] + r] = t;
    }
    goff[b * 513 + t] = off[t];
    if (t == 0) goff[b * 513 + 512] = off[512];
}

// ---------------- merge: float4 gather-mean per dst token (+mask) ----------------
__global__ __launch_bounds__(192) void merge_k(const float* __restrict__ hs,
                                               const int* __restrict__ goff,
                                               const int* __restrict__ glist,
                                               float* __restrict__ out){
    int bid = blockIdx.x;
    int b = bid / DT_, jj = bid - b * DT_;
    long obase4 = ((long)b * DT_ + jj) * (D_ / 4);
    float4* out4 = (float4*)out;
    if (threadIdx.x == 0) out[(long)B_ * DT_ * D_ + b * DT_ + jj] = 0.0f;  // mask
    int d = threadIdx.x;
    if (jj == 0){  // unmerged token = src[0] = seq 0
        const float4* src = (const float4*)(hs + (long)b * L_ * D_);
        out4[obase4 + d] = src[d];
        return;
    }
    int j = jj - 1;
    int o0 = goff[b * 513 + j], o1 = goff[b * 513 + j + 1];
    const float4* dst = (const float4*)(hs + ((long)b * L_ + 2 * j + 1) * D_);
    float4 a = dst[d];
    for (int s = o0; s < o1; ++s){   // ascending source index: deterministic
        int i = glist[b * T_ + s];
        const float4* srow = (const float4*)(hs + ((long)b * L_ + 2 * i) * D_);
        float4 v = srow[d];
        a.x += v.x; a.y += v.y; a.z += v.z; a.w += v.w;
    }
    float rc = 1.0f / (float)(o1 - o0 + 1);
    a.x *= rc; a.y *= rc; a.z *= rc; a.w *= rc;
    out4[obase4 + d] = a;
}

extern "C" void kernel_launch(void* const* d_in, const int* in_sizes, int n_in,
                              void* d_out, int out_size, void* d_ws, size_t ws_size,
                              hipStream_t stream){
    const float* hs = (const float*)d_in[0];  // (128,1024,768) f32
    float* out = (float*)d_out;
    char* ws = (char*)d_ws;

    const long PSZ = (long)B_ * CH_ * T_ * 8;          // 50,331,648 shorts = 100.66 MB
    unsigned short* Apk = (unsigned short*)ws;
    unsigned short* Bpk = Apk + PSZ;                   // ends at 201,326,592 B
    double* nsq      = (double*)(ws + 201326592);      // 1 MB (odd entries)
    int*    node_idx = (int*)   (ws + 202375168);      // 256 KB
    unsigned long long* rowkey = (unsigned long long*)(ws + 202637312); // 512 KB
    int*    paircnt  = (int*)   (ws + 203161600);      // 256 B
    int*    goff     = (int*)   (ws + 203161856);      // 263168 B
    int*    glist    = (int*)   (ws + 203425024);      // 262144 B
    int2*   pairs    = (int2*)  (ws + 203687168);      // 268.4 MB cap (worst case)

    pack_k  <<<B_ * 64, 256, 0, stream>>>(hs, Apk, Bpk, nsq, paircnt);
    coarse_k<<<512, 512, 0, stream>>>(Apk, Bpk, node_idx, rowkey, paircnt, pairs);
    refine_k<<<512, 256, 0, stream>>>(hs, nsq, paircnt, pairs, rowkey);
    csr_k   <<<B_, 512, 0, stream>>>(node_idx, rowkey, goff, glist);
    merge_k <<<B_ * DT_, 192, 0, stream>>>(hs, goff, glist, out);
}